// Round 6
// baseline (538.018 us; speedup 1.0000x reference)
//
#include <hip/hip_runtime.h>
#include <hip/hip_bf16.h>

#define S_LEN 2048
#define HID 4096
#define NH 32
#define NKV 8
#define DH 128
#define QKV_N ((NH + 2 * NKV) * DH) /* 6144 */
#define SCALE_ATT 0.08838834764831845f /* 128^-0.5 */
#define SCALE2_ATT 0.12751744f         /* SCALE_ATT * log2(e) */

typedef __bf16 bf16;
typedef __bf16 bf16x8 __attribute__((ext_vector_type(8)));
typedef __bf16 bf16x4 __attribute__((ext_vector_type(4)));
typedef float f32x4 __attribute__((ext_vector_type(4)));
typedef float f32x16 __attribute__((ext_vector_type(16)));

__device__ inline f32x4 mfma16(bf16x8 a, bf16x8 b, f32x4 c) {
    return __builtin_amdgcn_mfma_f32_16x16x32_bf16(a, b, c, 0, 0, 0);
}
__device__ inline f32x16 mfma32(bf16x8 a, bf16x8 b, f32x16 c) {
    return __builtin_amdgcn_mfma_f32_32x32x16_bf16(a, b, c, 0, 0, 0);
}

__device__ inline bf16x8 load8(const float* p) {
    const float4 a = ((const float4*)p)[0];
    const float4 b = ((const float4*)p)[1];
    bf16x8 r;
    r[0] = (bf16)a.x; r[1] = (bf16)a.y; r[2] = (bf16)a.z; r[3] = (bf16)a.w;
    r[4] = (bf16)b.x; r[5] = (bf16)b.y; r[6] = (bf16)b.z; r[7] = (bf16)b.w;
    return r;
}
__device__ inline bf16x8 load8(const bf16* p) { return *(const bf16x8*)p; }

// direct global->LDS DMA, 16 bytes/lane. LDS dest is wave-uniform base + lane*16.
__device__ inline void load_lds16(const bf16* g, bf16* lds_base) {
    __builtin_amdgcn_global_load_lds(
        (const __attribute__((address_space(1))) void*)g,
        (__attribute__((address_space(3))) void*)lds_base, 16, 0, 0);
}

// pack 2 f32 -> 1 u32 holding 2 bf16
__device__ inline unsigned pack2_bf16(float lo, float hi) {
    union { bf16 h[2]; unsigned u; } r;
    r.h[0] = (bf16)lo;
    r.h[1] = (bf16)hi;
    return r.u;
}

// fused fp32 -> bf16 bulk convert for three buffers (one launch)
__global__ __launch_bounds__(256) void cvt3_kernel(const float* __restrict__ s0, bf16* __restrict__ d0, int c0,
                                                   const float* __restrict__ s1, bf16* __restrict__ d1, int c1,
                                                   const float* __restrict__ s2, bf16* __restrict__ d2, int c2) {
    int i = blockIdx.x * 256 + threadIdx.x;
    if (i < c0) { *(bf16x8*)&d0[(size_t)i * 8] = load8(&s0[(size_t)i * 8]); return; }
    i -= c0;
    if (i < c1) { *(bf16x8*)&d1[(size_t)i * 8] = load8(&s1[(size_t)i * 8]); return; }
    i -= c1;
    if (i < c2) { *(bf16x8*)&d2[(size_t)i * 8] = load8(&s2[(size_t)i * 8]); }
}

// ---------------------------------------------------------------------------
// 256-row-tile GEMM, 4-phase/K-tile interleave, MINIMAL barrier set (2/tile).
// C[M x N] = A[M x K] @ B[N x K]^T, bf16 in. BM=256, BN in {256,128}, BK=64.
// 512 threads = 8 waves (2M x 4N), per-wave output 128 x BN/4, 32x32x16 MFMA.
// Per K-tile u (parity p), 4 phases (q = C-quadrant, 32 M-rows each):
//   ph0: ds_read all B-frags + A-q0 | stage A_{u+1} h0 -> p^1
//   ph1: ds_read A-q1              | stage A_{u+1} h1 -> p^1
//   [BARRIER_A] (all waves past ph0 B-reads -> B_{u+2} DMA may target parity p)
//   ph2: ds_read A-q2              | stage B_{u+2} h0 -> p
//   ph3: ds_read A-q3              | stage B_{u+2} h1 -> p
//   vmcnt(4|2) (counted: B_{u+2} stays in flight) [BARRIER_B] (publish A_{u+1};
//   orders this tile's A-reads before next tile's A-DMA into parity p)
// Hazard audit (round-5 -> round-6 barrier reduction):
//  - B_{u+2} DMA (ph2/3, parity p) vs B_u reads (ph0, parity p): BARRIER_A.
//  - A_{u+1} DMA (ph0/1, parity p^1) vs A-reads of p^1 (tile u-1): BARRIER_B
//    of tile u-1 interposes.
//  - staged-data consumption: vmcnt arithmetic identical to round 5 (B two
//    tiles ahead, A one ahead; queue at ph3 wait = B_{u+1}(4|2) oldest,
//    A_{u+1}(4), B_{u+2}(4|2) -> vmcnt leaves only B_{u+2}).
// Per-wave phase order (ds_read -> lgkmcnt(0) -> sched_barrier -> MFMA) kept.
// ---------------------------------------------------------------------------
template <int BN, typename OutT>
__global__ __launch_bounds__(512, 2) void gemm_8ph(const bf16* __restrict__ A,
                                                   const bf16* __restrict__ B,
                                                   OutT* __restrict__ C,
                                                   int K, int lda, int ldc) {
    constexpr int WTN = BN / 4;     // per-wave N extent
    constexpr int NREP = WTN / 32;  // 32-wide frags per wave (2 or 1)
    extern __shared__ char smem[];
    bf16* As = (bf16*)smem;                       // [2][256*64]
    bf16* Bs = (bf16*)(smem + 2 * 256 * 64 * 2);  // [2][BN*64]

    const int tid = threadIdx.x;
    const int lane = tid & 63;
    const int w = tid >> 6;     // 0..7
    const int wm = w >> 2;      // 0..1
    const int wn = w & 3;       // 0..3
    const int ln = lane & 31;
    const int hi = lane >> 5;
    const int rseg = lane >> 3;       // row within 8-row staging group
    const int gc = (lane & 7) ^ rseg; // swizzled source chunk

    const int m0 = (int)blockIdx.y * 256;
    const int n0 = (int)blockIdx.x * BN;
    const int NT = K >> 6;

    // stage A half h (128 rows) of k-tile kt into parity pb: 2 DMA calls
    auto stageA = [&](int pb, int kt, int h) {
        const int k0 = kt * 64;
        const int rb = h * 128 + w * 16;
        const bf16* src = &A[(size_t)(m0 + rb + rseg) * lda + k0 + gc * 8];
        bf16* dst = &As[pb * (256 * 64) + rb * 64];
        load_lds16(src, dst);
        load_lds16(src + (size_t)8 * lda, dst + 8 * 64);
    };
    // stage B half h of k-tile kt into parity pb: 2 calls (BN=256) or 1 (BN=128)
    auto stageB = [&](int pb, int kt, int h) {
        const int k0 = kt * 64;
        if constexpr (BN == 256) {
            const int rb = h * 128 + w * 16;
            const bf16* src = &B[(size_t)(n0 + rb + rseg) * K + k0 + gc * 8];
            bf16* dst = &Bs[pb * (BN * 64) + rb * 64];
            load_lds16(src, dst);
            load_lds16(src + (size_t)8 * K, dst + 8 * 64);
        } else {
            const int rb = h * 64 + w * 8;
            const bf16* src = &B[(size_t)(n0 + rb + rseg) * K + k0 + gc * 8];
            bf16* dst = &Bs[pb * (BN * 64) + rb * 64];
            load_lds16(src, dst);
        }
    };

    f32x16 acc[4][NREP];
#pragma unroll
    for (int mi = 0; mi < 4; ++mi)
#pragma unroll
        for (int j = 0; j < NREP; ++j)
#pragma unroll
            for (int r = 0; r < 16; ++r) acc[mi][j][r] = 0.f;

    // prologue: B_0, A_0 -> parity 0; B_1 -> parity 1 (stream order = steady state)
    stageB(0, 0, 0); stageB(0, 0, 1);
    stageA(0, 0, 0); stageA(0, 0, 1);
    {
        const int k1 = NT > 1 ? 1 : 0;
        stageB(1, k1, 0); stageB(1, k1, 1);
    }
    if constexpr (BN == 256)
        asm volatile("s_waitcnt vmcnt(4)" ::: "memory"); // B_0 + A_0 landed
    else
        asm volatile("s_waitcnt vmcnt(2)" ::: "memory");
    __builtin_amdgcn_s_barrier();

    int p = 0;
    for (int u = 0; u < NT; ++u, p ^= 1) {
        const bf16* Ab = &As[p * (256 * 64)];
        const bf16* Bb = &Bs[p * (BN * 64)];
        const int ktA = u + 1 < NT ? u + 1 : NT - 1; // clamped re-stage (never read)
        const int ktB = u + 2 < NT ? u + 2 : NT - 1;
        bf16x8 bfr[NREP][4];
#pragma unroll
        for (int q = 0; q < 4; ++q) {
            if (q == 2) __builtin_amdgcn_s_barrier(); // BARRIER_A
            if (q == 0) {
#pragma unroll
                for (int j = 0; j < NREP; ++j)
#pragma unroll
                    for (int kk = 0; kk < 4; ++kk) {
                        const int n = wn * WTN + j * 32 + ln;
                        bfr[j][kk] = *(const bf16x8*)&Bb[n * 64 + (((2 * kk + hi) ^ (ln & 7)) * 8)];
                    }
            }
            bf16x8 af[4];
#pragma unroll
            for (int kk = 0; kk < 4; ++kk) {
                const int m = wm * 128 + q * 32 + ln;
                af[kk] = *(const bf16x8*)&Ab[m * 64 + (((2 * kk + hi) ^ (ln & 7)) * 8)];
            }
            if (q == 0) stageA(p ^ 1, ktA, 0);
            else if (q == 1) stageA(p ^ 1, ktA, 1);
            else if (q == 2) stageB(p, ktB, 0);
            else stageB(p, ktB, 1);

            asm volatile("s_waitcnt lgkmcnt(0)" ::: "memory");
            __builtin_amdgcn_sched_barrier(0);
            __builtin_amdgcn_s_setprio(1);
#pragma unroll
            for (int j = 0; j < NREP; ++j)
#pragma unroll
                for (int kk = 0; kk < 4; ++kk)
                    acc[q][j] = mfma32(af[kk], bfr[j][kk], acc[q][j]);
            __builtin_amdgcn_s_setprio(0);
            __builtin_amdgcn_sched_barrier(0);
            if (q == 3) {
                if constexpr (BN == 256)
                    asm volatile("s_waitcnt vmcnt(4)" ::: "memory"); // A_{u+1}+B_{u+1} landed
                else
                    asm volatile("s_waitcnt vmcnt(2)" ::: "memory");
                __builtin_amdgcn_s_barrier(); // BARRIER_B
            }
        }
    }
    asm volatile("s_waitcnt vmcnt(0)" ::: "memory"); // drain clamped garbage stages

    // epilogue: C[row][col], row from A-frag index, col = ln (attn-verified map)
#pragma unroll
    for (int mi = 0; mi < 4; ++mi)
#pragma unroll
        for (int j = 0; j < NREP; ++j)
#pragma unroll
            for (int r = 0; r < 16; ++r) {
                int row = m0 + wm * 128 + mi * 32 + (r & 3) + 8 * (r >> 2) + 4 * hi;
                int col = n0 + wn * WTN + j * 32 + ln;
                C[(size_t)row * ldc + col] = (OutT)acc[mi][j][r];
            }
}

// ---------------- fallback fp32-staging GEMM (low-workspace path) ----------------
template <typename AT, typename OutT>
__global__ __launch_bounds__(256) void gemm_bt(const AT* __restrict__ A,
                                               const float* __restrict__ B,
                                               OutT* __restrict__ C,
                                               int K, int lda, int ldc) {
    const int tid = threadIdx.x;
    const int lane = tid & 63;
    const int w = tid >> 6;
    const int m0 = blockIdx.y * 128;
    const int n0 = blockIdx.x * 128;
    const int wm = (w >> 1) * 64;
    const int wn = (w & 1) * 64;
    const int ln = lane & 15;
    const int qo = lane >> 4;

    __shared__ bf16 As[128 * 72];
    __shared__ bf16 Bs[128 * 72];

    f32x4 acc[4][4];
#pragma unroll
    for (int mi = 0; mi < 4; ++mi)
#pragma unroll
        for (int ni = 0; ni < 4; ++ni) acc[mi][ni] = f32x4{0.f, 0.f, 0.f, 0.f};

    for (int k0 = 0; k0 < K; k0 += 64) {
#pragma unroll
        for (int i = 0; i < 4; ++i) {
            int v = tid + i * 256;
            int row = v >> 3;
            int col = (v & 7) * 8;
            *(bf16x8*)&As[row * 72 + col] = load8(&A[(size_t)(m0 + row) * lda + k0 + col]);
            *(bf16x8*)&Bs[row * 72 + col] = load8(&B[(size_t)(n0 + row) * K + k0 + col]);
        }
        __syncthreads();
#pragma unroll
        for (int kk = 0; kk < 64; kk += 32) {
            bf16x8 af[4], bfr[4];
#pragma unroll
            for (int mi = 0; mi < 4; ++mi)
                af[mi] = *(const bf16x8*)&As[(wm + mi * 16 + ln) * 72 + kk + qo * 8];
#pragma unroll
            for (int ni = 0; ni < 4; ++ni)
                bfr[ni] = *(const bf16x8*)&Bs[(wn + ni * 16 + ln) * 72 + kk + qo * 8];
#pragma unroll
            for (int mi = 0; mi < 4; ++mi)
#pragma unroll
                for (int ni = 0; ni < 4; ++ni)
                    acc[mi][ni] = mfma16(af[mi], bfr[ni], acc[mi][ni]);
        }
        __syncthreads();
    }
#pragma unroll
    for (int mi = 0; mi < 4; ++mi)
#pragma unroll
        for (int ni = 0; ni < 4; ++ni)
#pragma unroll
            for (int r = 0; r < 4; ++r) {
                int row = m0 + wm + mi * 16 + qo * 4 + r;
                int col = n0 + wn + ni * 16 + ln;
                C[(size_t)row * ldc + col] = (OutT)acc[mi][ni][r];
            }
}

// RoPE: one thread per (s, d) pair; trig computed ONCE and reused across all
// 40 rotated heads (q heads 0..31 and k heads 32..39 are contiguous at h*DH).
// Round-5 version computed 5.24M transcendental triples; unique count is
// S*64 = 131K (40x redundancy). Wave = one s, d 0..63 -> 128B coalesced rows.
__global__ __launch_bounds__(256) void rope_kernel(bf16* __restrict__ qkv,
                                                   const int* __restrict__ positions) {
    int idx = blockIdx.x * 256 + threadIdx.x;
    if (idx >= S_LEN * 64) return;
    int d = idx & 63;
    int s = idx >> 6;
    float pos = (float)positions[s];
    float inv = expf(-0.21586735246819178f * (float)d); // 1e6^(-d/64)
    float ang = pos * inv;
    float sn, c;
    sincosf(ang, &sn, &c);
    const size_t row = (size_t)s * QKV_N;
#pragma unroll 8
    for (int h = 0; h < NH + NKV; ++h) {
        size_t base = row + (size_t)h * DH;
        float x1 = (float)qkv[base + d];
        float x2 = (float)qkv[base + d + 64];
        qkv[base + d] = (bf16)(x1 * c - x2 * sn);
        qkv[base + d + 64] = (bf16)(x2 * c + x1 * sn);
    }
}

// Pre-transpose V into vt_g[kvh][d][s]
__global__ __launch_bounds__(256) void vtrans_kernel(const bf16* __restrict__ qkv,
                                                     bf16* __restrict__ vt_g) {
    const int tid = threadIdx.x;
    const int s0 = blockIdx.x * 64;
    const int kvh = blockIdx.y;
    __shared__ bf16 Ls[64 * 136];
#pragma unroll
    for (int i = 0; i < 4; ++i) {
        int v = tid + i * 256;
        int row = v >> 4;
        int col = (v & 15) * 8;
        *(bf16x8*)&Ls[row * 136 + col] =
            *(const bf16x8*)&qkv[(size_t)(s0 + row) * QKV_N + (NH + NKV) * DH + kvh * DH + col];
    }
    __syncthreads();
#pragma unroll
    for (int i = 0; i < 4; ++i) {
        int u = tid + i * 256;
        int d = u >> 3;
        int sg = (u & 7) * 8;
        bf16x8 r;
#pragma unroll
        for (int j = 0; j < 8; ++j) r[j] = Ls[(sg + j) * 136 + d];
        *(bf16x8*)&vt_g[((size_t)kvh * DH + d) * S_LEN + s0 + sg] = r;
    }
}

// ---------------------------------------------------------------------------
// Flash attention (round-2 proven structure + T13 defer-max): 4 warps x 32
// q-rows, KVBLK=64, 32x32x16 MFMA, swapped QK^T, in-register softmax, shfl
// cross-half P exchange, O^T = Vt @ P^T, XOR-swizzled LDS via global_load_lds,
// 1 barrier/tile. Defer-max: skip the 64-mul acc rescale when the tile max
// is within 11.5 (log2 domain, = 8 nats, HK THR) of the running max.
// ---------------------------------------------------------------------------
__global__ __launch_bounds__(256) void attn_kernel(bf16* __restrict__ qkv,
                                                   const bf16* __restrict__ vt_g) {
    const int tid = threadIdx.x;
    const int lane = tid & 63;
    const int w = tid >> 6;
    const int ln = lane & 31;
    const int hi = lane >> 5;
    const int hq = blockIdx.x;
    const int qtile = (int)gridDim.y - 1 - (int)blockIdx.y; // heavy first
    const int kvh = hq >> 2;
    const int q0 = qtile * 128;
    const int qrow = q0 + w * 32 + ln;

    __shared__ __align__(128) bf16 Ks[2][64 * 128];
    __shared__ __align__(128) bf16 Vt[2][128 * 64];

    bf16x8 qf[8];
    {
        const bf16* qptr = qkv + (size_t)qrow * QKV_N + hq * DH + hi * 8;
#pragma unroll
        for (int s = 0; s < 8; ++s) qf[s] = *(const bf16x8*)(qptr + s * 16);
    }

    const bf16* ksrc = qkv + NH * DH + kvh * DH;
    const bf16* vsrc = vt_g + (size_t)kvh * DH * S_LEN;
    const int kcK = lane & 15;
    const int krs = lane >> 4;
    const int kcV = lane & 7;
    const int vrs = lane >> 3;

    auto stage = [&](int buf, int kt) {
        const int k0s = kt * 64;
#pragma unroll
        for (int j = 0; j < 4; ++j) {
            int r = w * 16 + j * 4 + krs;
            load_lds16(ksrc + (size_t)(k0s + r) * QKV_N + ((kcK ^ (r & 7)) * 8),
                       &Ks[buf][(w * 16 + j * 4) * 128]);
        }
#pragma unroll
        for (int j = 0; j < 4; ++j) {
            int d = w * 32 + j * 8 + vrs;
            load_lds16(vsrc + (size_t)d * S_LEN + k0s + ((kcV ^ (d & 7)) * 8),
                       &Vt[buf][(w * 32 + j * 8) * 64]);
        }
    };

    f32x16 acc[4];
#pragma unroll
    for (int t = 0; t < 4; ++t)
#pragma unroll
        for (int r = 0; r < 16; ++r) acc[t][r] = 0.f;
    float m2 = -1e30f, l = 0.f;

    const int kt_last = (q0 + 127) >> 6;
    int buf = 0;
    stage(0, 0);
    __syncthreads();

    for (int kt = 0; kt <= kt_last; ++kt) {
        if (kt < kt_last) stage(buf ^ 1, kt + 1);
        const int k0 = kt * 64;
        if (k0 <= q0 + w * 32 + 31) {
            f32x16 st[2];
#pragma unroll
            for (int t = 0; t < 2; ++t)
#pragma unroll
                for (int r = 0; r < 16; ++r) st[t][r] = 0.f;
            const bf16* Kb = &Ks[buf][0];
            __builtin_amdgcn_s_setprio(1);
#pragma unroll
            for (int t = 0; t < 2; ++t) {
                const int key = t * 32 + ln;
#pragma unroll
                for (int s = 0; s < 8; ++s) {
                    bf16x8 kf =
                        *(const bf16x8*)&Kb[key * 128 + (((2 * s + hi) ^ (key & 7)) * 8)];
                    st[t] = mfma32(kf, qf[s], st[t]);
                }
            }
            __builtin_amdgcn_s_setprio(0);
            const bool needMask = (k0 + 63 > q0 + w * 32);
            float tmax = -1e30f;
#pragma unroll
            for (int t = 0; t < 2; ++t)
#pragma unroll
                for (int r = 0; r < 16; ++r) {
                    int kcol = k0 + t * 32 + (r & 3) + 8 * (r >> 2) + 4 * hi;
                    float v = st[t][r] * SCALE2_ATT;
                    if (needMask && kcol > qrow) v = -1e30f;
                    st[t][r] = v;
                    tmax = fmaxf(tmax, v);
                }
            tmax = fmaxf(tmax, __shfl_xor(tmax, 32, 64));
            // T13 defer-max: keep old running max when growth is small
            const bool skip = __all(tmax - m2 <= 11.5f);
            float mnew, alpha;
            if (skip) { mnew = m2; alpha = 1.f; }
            else { mnew = fmaxf(m2, tmax); alpha = exp2f(m2 - mnew); }
            float rs = 0.f;
#pragma unroll
            for (int t = 0; t < 2; ++t)
#pragma unroll
                for (int r = 0; r < 16; ++r) {
                    float e = exp2f(st[t][r] - mnew);
                    st[t][r] = e;
                    rs += e;
                }
            rs += __shfl_xor(rs, 32, 64);
            l = l * alpha + rs;
            m2 = mnew;
            if (!skip) {
#pragma unroll
                for (int t = 0; t < 4; ++t)
#pragma unroll
                    for (int r = 0; r < 16; ++r) acc[t][r] *= alpha;
            }
            unsigned cw[16];
#pragma unroll
            for (int i = 0; i < 16; ++i)
                cw[i] = pack2_bf16(st[i >> 3][2 * (i & 7)], st[i >> 3][2 * (i & 7) + 1]);
            bf16x8 pa[4];
#pragma unroll
            for (int ks = 0; ks < 4; ++ks) {
                const int base = (ks >> 1) * 8 + (ks & 1) * 4;
                union { unsigned u[4]; bf16x8 v; } pk;
#pragma unroll
                for (int e = 0; e < 2; ++e) {
                    unsigned A = cw[base + e];
                    unsigned B = cw[base + 2 + e];
                    unsigned tA = (unsigned)__shfl_xor((int)A, 32, 64);
                    unsigned tB = (unsigned)__shfl_xor((int)B, 32, 64);
                    pk.u[e] = hi ? tB : A;
                    pk.u[e + 2] = hi ? B : tA;
                }
                pa[ks] = pk.v;
            }
            const bf16* Vb = &Vt[buf][0];
            __builtin_amdgcn_s_setprio(1);
#pragma unroll
            for (int dt = 0; dt < 4; ++dt) {
                const int d = dt * 32 + ln;
#pragma unroll
                for (int ks = 0; ks < 4; ++ks) {
                    bf16x8 vf =
                        *(const bf16x8*)&Vb[d * 64 + (((2 * ks + hi) ^ (d & 7)) * 8)];
                    acc[dt] = mfma32(vf, pa[ks], acc[dt]);
                }
            }
            __builtin_amdgcn_s_setprio(0);
        }
        __syncthreads();
        buf ^= 1;
    }

    const float invl = 1.f / l;
    bf16* outp = qkv + (size_t)qrow * QKV_N + hq * DH;
#pragma unroll
    for (int dt = 0; dt < 4; ++dt)
#pragma unroll
        for (int rq = 0; rq < 4; ++rq) {
            bf16x4 o;
#pragma unroll
            for (int i = 0; i < 4; ++i) o[i] = (bf16)(acc[dt][rq * 4 + i] * invl);
            *(bf16x4*)(outp + dt * 32 + rq * 8 + hi * 4) = o;
        }
}

extern "C" void kernel_launch(void* const* d_in, const int* in_sizes, int n_in,
                              void* d_out, int out_size, void* d_ws, size_t ws_size,
                              hipStream_t stream) {
    const int* positions = (const int*)d_in[0];
    const float* hidden = (const float*)d_in[1];
    const float* w_qkv = (const float*)d_in[2];
    const float* w_o = (const float*)d_in[3];
    float* out = (float*)d_out;

    const size_t n_qkv = (size_t)S_LEN * QKV_N;
    const size_t n_vt = (size_t)NKV * DH * S_LEN;
    const size_t n_hid = (size_t)S_LEN * HID;
    const size_t n_wqkv = (size_t)QKV_N * HID;
    const size_t n_wo = (size_t)HID * HID;

    const size_t need_min = (n_qkv + n_vt) * sizeof(bf16);
    const size_t need_full = (n_qkv + n_vt + n_hid + n_wqkv + n_wo) * sizeof(bf16);
    if (ws_size < need_min) return;

    bf16* qkv = (bf16*)d_ws;
    bf16* vt_g = qkv + n_qkv;
    bf16* hid_b = vt_g + n_vt;
    bf16* wqkv_b = hid_b + n_hid;
    bf16* wo_b = wqkv_b + n_wqkv;
    const bool full = ws_size >= need_full;

    if (full) {
        const int c0 = (int)(n_hid / 8), c1 = (int)(n_wqkv / 8), c2 = (int)(n_wo / 8);
        cvt3_kernel<<<(c0 + c1 + c2 + 255) / 256, 256, 0, stream>>>(hidden, hid_b, c0,
                                                                    w_qkv, wqkv_b, c1,
                                                                    w_o, wo_b, c2);
        hipFuncSetAttribute(reinterpret_cast<const void*>(&gemm_8ph<256, bf16>),
                            hipFuncAttributeMaxDynamicSharedMemorySize, 131072);
        gemm_8ph<256, bf16><<<dim3(QKV_N / 256, S_LEN / 256), 512, 131072, stream>>>(
            hid_b, wqkv_b, qkv, HID, HID, QKV_N);
    } else {
        gemm_bt<<<dim3(QKV_N / 128, S_LEN / 128), 256, 0, stream>>>(hidden, w_qkv, qkv, HID, HID, QKV_N);
    }
    rope_kernel<<<(S_LEN * 64 + 255) / 256, 256, 0, stream>>>(qkv, positions);
    vtrans_kernel<<<dim3(S_LEN / 64, NKV), 256, 0, stream>>>(qkv, vt_g);
    attn_kernel<<<dim3(NH, S_LEN / 128), 256, 0, stream>>>(qkv, vt_g);
    if (full) {
        hipFuncSetAttribute(reinterpret_cast<const void*>(&gemm_8ph<128, float>),
                            hipFuncAttributeMaxDynamicSharedMemorySize, 98304);
        gemm_8ph<128, float><<<dim3(HID / 128, S_LEN / 256), 512, 98304, stream>>>(
            qkv, wo_b, out, HID, QKV_N, HID);
    } else {
        gemm_bt<<<dim3(HID / 128, S_LEN / 128), 256, 0, stream>>>(qkv, w_o, out, HID, QKV_N, HID);
    }
}

// Round 7
// 525.556 us; speedup vs baseline: 1.0237x; 1.0237x over previous
//
#include <hip/hip_runtime.h>
#include <hip/hip_bf16.h>

#define S_LEN 2048
#define HID 4096
#define NH 32
#define NKV 8
#define DH 128
#define QKV_N ((NH + 2 * NKV) * DH) /* 6144 */
#define SCALE_ATT 0.08838834764831845f /* 128^-0.5 */
#define SCALE2_ATT 0.12751744f         /* SCALE_ATT * log2(e) */

typedef __bf16 bf16;
typedef __bf16 bf16x8 __attribute__((ext_vector_type(8)));
typedef __bf16 bf16x4 __attribute__((ext_vector_type(4)));
typedef float f32x4 __attribute__((ext_vector_type(4)));
typedef float f32x16 __attribute__((ext_vector_type(16)));

__device__ inline f32x4 mfma16(bf16x8 a, bf16x8 b, f32x4 c) {
    return __builtin_amdgcn_mfma_f32_16x16x32_bf16(a, b, c, 0, 0, 0);
}
__device__ inline f32x16 mfma32(bf16x8 a, bf16x8 b, f32x16 c) {
    return __builtin_amdgcn_mfma_f32_32x32x16_bf16(a, b, c, 0, 0, 0);
}

__device__ inline bf16x8 load8(const float* p) {
    const float4 a = ((const float4*)p)[0];
    const float4 b = ((const float4*)p)[1];
    bf16x8 r;
    r[0] = (bf16)a.x; r[1] = (bf16)a.y; r[2] = (bf16)a.z; r[3] = (bf16)a.w;
    r[4] = (bf16)b.x; r[5] = (bf16)b.y; r[6] = (bf16)b.z; r[7] = (bf16)b.w;
    return r;
}
__device__ inline bf16x8 load8(const bf16* p) { return *(const bf16x8*)p; }

// direct global->LDS DMA, 16 bytes/lane. LDS dest is wave-uniform base + lane*16.
__device__ inline void load_lds16(const bf16* g, bf16* lds_base) {
    __builtin_amdgcn_global_load_lds(
        (const __attribute__((address_space(1))) void*)g,
        (__attribute__((address_space(3))) void*)lds_base, 16, 0, 0);
}

// pack 2 f32 -> 1 u32 holding 2 bf16
__device__ inline unsigned pack2_bf16(float lo, float hi) {
    union { bf16 h[2]; unsigned u; } r;
    r.h[0] = (bf16)lo;
    r.h[1] = (bf16)hi;
    return r.u;
}

// fused fp32 -> bf16 bulk convert for three buffers (one launch)
__global__ __launch_bounds__(256) void cvt3_kernel(const float* __restrict__ s0, bf16* __restrict__ d0, int c0,
                                                   const float* __restrict__ s1, bf16* __restrict__ d1, int c1,
                                                   const float* __restrict__ s2, bf16* __restrict__ d2, int c2) {
    int i = blockIdx.x * 256 + threadIdx.x;
    if (i < c0) { *(bf16x8*)&d0[(size_t)i * 8] = load8(&s0[(size_t)i * 8]); return; }
    i -= c0;
    if (i < c1) { *(bf16x8*)&d1[(size_t)i * 8] = load8(&s1[(size_t)i * 8]); return; }
    i -= c1;
    if (i < c2) { *(bf16x8*)&d2[(size_t)i * 8] = load8(&s2[(size_t)i * 8]); }
}

// ---------------------------------------------------------------------------
// 256-row-tile GEMM, 2 half-phases/K-tile, COMPILER-SCHEDULED inner bodies.
// C[M x N] = A[M x K] @ B[N x K]^T, bf16 in. BM=256, BN in {256,128}, BK=64.
// 512 threads = 8 waves (2M x 4N), per-wave output 128 x BN/4, 32x32x16 MFMA.
// Round-7 theory: kernel is LDS-port-bound (192KB reads + 64KB DMA writes
// per tile per CU ~ 3000 cyc at 85 B/cyc ceiling; MFMA only 512). Rounds 4-6
// forced lgkmcnt(0)+sched_barrier before every MFMA cluster -> port idles
// (54 B/cyc sustained). Fix: NO pins inside the half-phase; compiler emits
// fine-grained lgkmcnt interleaving ds_read with MFMA (m97 behavior). The
// only required lgkmcnt(0) is the WAR drain immediately before each barrier
// (my reads must complete before other waves' DMA overwrites the slot).
// Per K-tile u (parity p):
//   half1: ds_read B-frags + A-q0,q1 | stage A_{u+1} -> p^1 | MFMA q0,q1
//          lgkmcnt(0); BARRIER_A   (B-reads of p done -> B DMA may target p)
//   half2: ds_read A-q2,q3          | stage B_{u+2} -> p    | MFMA q2,q3
//          vmcnt(4|2) (A_{u+1}+B_{u+1} landed, B_{u+2} stays in flight);
//          lgkmcnt(0); BARRIER_B   (publish next tile; A-read WAR drain)
// Hazard audit unchanged from round 6 (same barrier pair, same vmcnt queue:
// at BARRIER_B outstanding = B_{u+1}(4|2), A_{u+1}(4), B_{u+2}(4|2)).
// ---------------------------------------------------------------------------
template <int BN, typename OutT>
__global__ __launch_bounds__(512, 2) void gemm_8ph(const bf16* __restrict__ A,
                                                   const bf16* __restrict__ B,
                                                   OutT* __restrict__ C,
                                                   int K, int lda, int ldc) {
    constexpr int WTN = BN / 4;     // per-wave N extent
    constexpr int NREP = WTN / 32;  // 32-wide frags per wave (2 or 1)
    extern __shared__ char smem[];
    bf16* As = (bf16*)smem;                       // [2][256*64]
    bf16* Bs = (bf16*)(smem + 2 * 256 * 64 * 2);  // [2][BN*64]

    const int tid = threadIdx.x;
    const int lane = tid & 63;
    const int w = tid >> 6;     // 0..7
    const int wm = w >> 2;      // 0..1
    const int wn = w & 3;       // 0..3
    const int ln = lane & 31;
    const int hi = lane >> 5;
    const int rseg = lane >> 3;       // row within 8-row staging group
    const int gc = (lane & 7) ^ rseg; // swizzled source chunk

    const int m0 = (int)blockIdx.y * 256;
    const int n0 = (int)blockIdx.x * BN;
    const int NT = K >> 6;

    // stage A half h (128 rows) of k-tile kt into parity pb: 2 DMA calls
    auto stageA = [&](int pb, int kt, int h) {
        const int k0 = kt * 64;
        const int rb = h * 128 + w * 16;
        const bf16* src = &A[(size_t)(m0 + rb + rseg) * lda + k0 + gc * 8];
        bf16* dst = &As[pb * (256 * 64) + rb * 64];
        load_lds16(src, dst);
        load_lds16(src + (size_t)8 * lda, dst + 8 * 64);
    };
    // stage B half h of k-tile kt into parity pb: 2 calls (BN=256) or 1 (BN=128)
    auto stageB = [&](int pb, int kt, int h) {
        const int k0 = kt * 64;
        if constexpr (BN == 256) {
            const int rb = h * 128 + w * 16;
            const bf16* src = &B[(size_t)(n0 + rb + rseg) * K + k0 + gc * 8];
            bf16* dst = &Bs[pb * (BN * 64) + rb * 64];
            load_lds16(src, dst);
            load_lds16(src + (size_t)8 * K, dst + 8 * 64);
        } else {
            const int rb = h * 64 + w * 8;
            const bf16* src = &B[(size_t)(n0 + rb + rseg) * K + k0 + gc * 8];
            bf16* dst = &Bs[pb * (BN * 64) + rb * 64];
            load_lds16(src, dst);
        }
    };

    f32x16 acc[4][NREP];
#pragma unroll
    for (int mi = 0; mi < 4; ++mi)
#pragma unroll
        for (int j = 0; j < NREP; ++j)
#pragma unroll
            for (int r = 0; r < 16; ++r) acc[mi][j][r] = 0.f;

    // prologue: B_0, A_0 -> parity 0; B_1 -> parity 1 (stream order = steady state)
    stageB(0, 0, 0); stageB(0, 0, 1);
    stageA(0, 0, 0); stageA(0, 0, 1);
    {
        const int k1 = NT > 1 ? 1 : 0;
        stageB(1, k1, 0); stageB(1, k1, 1);
    }
    if constexpr (BN == 256)
        asm volatile("s_waitcnt vmcnt(4)" ::: "memory"); // B_0 + A_0 landed
    else
        asm volatile("s_waitcnt vmcnt(2)" ::: "memory");
    __builtin_amdgcn_s_barrier();

    int p = 0;
    for (int u = 0; u < NT; ++u, p ^= 1) {
        const bf16* Ab = &As[p * (256 * 64)];
        const bf16* Bb = &Bs[p * (BN * 64)];
        const int ktA = u + 1 < NT ? u + 1 : NT - 1; // clamped re-stage (never read)
        const int ktB = u + 2 < NT ? u + 2 : NT - 1;

        // ---------------- half 1: B-frags + quadrants 0,1 ----------------
        bf16x8 bfr[NREP][4];
#pragma unroll
        for (int j = 0; j < NREP; ++j)
#pragma unroll
            for (int kk = 0; kk < 4; ++kk) {
                const int n = wn * WTN + j * 32 + ln;
                bfr[j][kk] = *(const bf16x8*)&Bb[n * 64 + (((2 * kk + hi) ^ (ln & 7)) * 8)];
            }
        {
            bf16x8 af0[4], af1[4];
#pragma unroll
            for (int kk = 0; kk < 4; ++kk) {
                const int mA = wm * 128 + 0 * 32 + ln;
                const int mB = wm * 128 + 1 * 32 + ln;
                af0[kk] = *(const bf16x8*)&Ab[mA * 64 + (((2 * kk + hi) ^ (ln & 7)) * 8)];
                af1[kk] = *(const bf16x8*)&Ab[mB * 64 + (((2 * kk + hi) ^ (ln & 7)) * 8)];
            }
            stageA(p ^ 1, ktA, 0);
            stageA(p ^ 1, ktA, 1);
#pragma unroll
            for (int j = 0; j < NREP; ++j)
#pragma unroll
                for (int kk = 0; kk < 4; ++kk) {
                    acc[0][j] = mfma32(af0[kk], bfr[j][kk], acc[0][j]);
                    acc[1][j] = mfma32(af1[kk], bfr[j][kk], acc[1][j]);
                }
        }
        asm volatile("s_waitcnt lgkmcnt(0)" ::: "memory"); // WAR: my p-reads done
        __builtin_amdgcn_s_barrier();                      // BARRIER_A

        // ---------------- half 2: quadrants 2,3 ----------------
        {
            bf16x8 af2[4], af3[4];
#pragma unroll
            for (int kk = 0; kk < 4; ++kk) {
                const int mA = wm * 128 + 2 * 32 + ln;
                const int mB = wm * 128 + 3 * 32 + ln;
                af2[kk] = *(const bf16x8*)&Ab[mA * 64 + (((2 * kk + hi) ^ (ln & 7)) * 8)];
                af3[kk] = *(const bf16x8*)&Ab[mB * 64 + (((2 * kk + hi) ^ (ln & 7)) * 8)];
            }
            stageB(p, ktB, 0);
            stageB(p, ktB, 1);
#pragma unroll
            for (int j = 0; j < NREP; ++j)
#pragma unroll
                for (int kk = 0; kk < 4; ++kk) {
                    acc[2][j] = mfma32(af2[kk], bfr[j][kk], acc[2][j]);
                    acc[3][j] = mfma32(af3[kk], bfr[j][kk], acc[3][j]);
                }
        }
        if constexpr (BN == 256)
            asm volatile("s_waitcnt vmcnt(4)" ::: "memory"); // A_{u+1}+B_{u+1} landed
        else
            asm volatile("s_waitcnt vmcnt(2)" ::: "memory");
        asm volatile("s_waitcnt lgkmcnt(0)" ::: "memory");   // WAR: my A-reads done
        __builtin_amdgcn_s_barrier();                        // BARRIER_B
    }
    asm volatile("s_waitcnt vmcnt(0)" ::: "memory"); // drain clamped garbage stages

    // epilogue: C[row][col], row from A-frag index, col = ln (attn-verified map)
#pragma unroll
    for (int mi = 0; mi < 4; ++mi)
#pragma unroll
        for (int j = 0; j < NREP; ++j)
#pragma unroll
            for (int r = 0; r < 16; ++r) {
                int row = m0 + wm * 128 + mi * 32 + (r & 3) + 8 * (r >> 2) + 4 * hi;
                int col = n0 + wn * WTN + j * 32 + ln;
                C[(size_t)row * ldc + col] = (OutT)acc[mi][j][r];
            }
}

// ---------------- fallback fp32-staging GEMM (low-workspace path) ----------------
template <typename AT, typename OutT>
__global__ __launch_bounds__(256) void gemm_bt(const AT* __restrict__ A,
                                               const float* __restrict__ B,
                                               OutT* __restrict__ C,
                                               int K, int lda, int ldc) {
    const int tid = threadIdx.x;
    const int lane = tid & 63;
    const int w = tid >> 6;
    const int m0 = blockIdx.y * 128;
    const int n0 = blockIdx.x * 128;
    const int wm = (w >> 1) * 64;
    const int wn = (w & 1) * 64;
    const int ln = lane & 15;
    const int qo = lane >> 4;

    __shared__ bf16 As[128 * 72];
    __shared__ bf16 Bs[128 * 72];

    f32x4 acc[4][4];
#pragma unroll
    for (int mi = 0; mi < 4; ++mi)
#pragma unroll
        for (int ni = 0; ni < 4; ++ni) acc[mi][ni] = f32x4{0.f, 0.f, 0.f, 0.f};

    for (int k0 = 0; k0 < K; k0 += 64) {
#pragma unroll
        for (int i = 0; i < 4; ++i) {
            int v = tid + i * 256;
            int row = v >> 3;
            int col = (v & 7) * 8;
            *(bf16x8*)&As[row * 72 + col] = load8(&A[(size_t)(m0 + row) * lda + k0 + col]);
            *(bf16x8*)&Bs[row * 72 + col] = load8(&B[(size_t)(n0 + row) * K + k0 + col]);
        }
        __syncthreads();
#pragma unroll
        for (int kk = 0; kk < 64; kk += 32) {
            bf16x8 af[4], bfr[4];
#pragma unroll
            for (int mi = 0; mi < 4; ++mi)
                af[mi] = *(const bf16x8*)&As[(wm + mi * 16 + ln) * 72 + kk + qo * 8];
#pragma unroll
            for (int ni = 0; ni < 4; ++ni)
                bfr[ni] = *(const bf16x8*)&Bs[(wn + ni * 16 + ln) * 72 + kk + qo * 8];
#pragma unroll
            for (int mi = 0; mi < 4; ++mi)
#pragma unroll
                for (int ni = 0; ni < 4; ++ni)
                    acc[mi][ni] = mfma16(af[mi], bfr[ni], acc[mi][ni]);
        }
        __syncthreads();
    }
#pragma unroll
    for (int mi = 0; mi < 4; ++mi)
#pragma unroll
        for (int ni = 0; ni < 4; ++ni)
#pragma unroll
            for (int r = 0; r < 4; ++r) {
                int row = m0 + wm + mi * 16 + qo * 4 + r;
                int col = n0 + wn + ni * 16 + ln;
                C[(size_t)row * ldc + col] = (OutT)acc[mi][ni][r];
            }
}

// RoPE: one thread per (s, d) pair; trig computed once, reused across all 40
// rotated heads. Coalesced 128B rows per head.
__global__ __launch_bounds__(256) void rope_kernel(bf16* __restrict__ qkv,
                                                   const int* __restrict__ positions) {
    int idx = blockIdx.x * 256 + threadIdx.x;
    if (idx >= S_LEN * 64) return;
    int d = idx & 63;
    int s = idx >> 6;
    float pos = (float)positions[s];
    float inv = expf(-0.21586735246819178f * (float)d); // 1e6^(-d/64)
    float ang = pos * inv;
    float sn, c;
    sincosf(ang, &sn, &c);
    const size_t row = (size_t)s * QKV_N;
#pragma unroll 8
    for (int h = 0; h < NH + NKV; ++h) {
        size_t base = row + (size_t)h * DH;
        float x1 = (float)qkv[base + d];
        float x2 = (float)qkv[base + d + 64];
        qkv[base + d] = (bf16)(x1 * c - x2 * sn);
        qkv[base + d + 64] = (bf16)(x2 * c + x1 * sn);
    }
}

// Pre-transpose V into vt_g[kvh][d][s]
__global__ __launch_bounds__(256) void vtrans_kernel(const bf16* __restrict__ qkv,
                                                     bf16* __restrict__ vt_g) {
    const int tid = threadIdx.x;
    const int s0 = blockIdx.x * 64;
    const int kvh = blockIdx.y;
    __shared__ bf16 Ls[64 * 136];
#pragma unroll
    for (int i = 0; i < 4; ++i) {
        int v = tid + i * 256;
        int row = v >> 4;
        int col = (v & 15) * 8;
        *(bf16x8*)&Ls[row * 136 + col] =
            *(const bf16x8*)&qkv[(size_t)(s0 + row) * QKV_N + (NH + NKV) * DH + kvh * DH + col];
    }
    __syncthreads();
#pragma unroll
    for (int i = 0; i < 4; ++i) {
        int u = tid + i * 256;
        int d = u >> 3;
        int sg = (u & 7) * 8;
        bf16x8 r;
#pragma unroll
        for (int j = 0; j < 8; ++j) r[j] = Ls[(sg + j) * 136 + d];
        *(bf16x8*)&vt_g[((size_t)kvh * DH + d) * S_LEN + s0 + sg] = r;
    }
}

// ---------------------------------------------------------------------------
// Flash attention (round-2 proven structure + T13 defer-max): 4 warps x 32
// q-rows, KVBLK=64, 32x32x16 MFMA, swapped QK^T, in-register softmax, shfl
// cross-half P exchange, O^T = Vt @ P^T, XOR-swizzled LDS via global_load_lds,
// 1 barrier/tile.
// ---------------------------------------------------------------------------
__global__ __launch_bounds__(256) void attn_kernel(bf16* __restrict__ qkv,
                                                   const bf16* __restrict__ vt_g) {
    const int tid = threadIdx.x;
    const int lane = tid & 63;
    const int w = tid >> 6;
    const int ln = lane & 31;
    const int hi = lane >> 5;
    const int hq = blockIdx.x;
    const int qtile = (int)gridDim.y - 1 - (int)blockIdx.y; // heavy first
    const int kvh = hq >> 2;
    const int q0 = qtile * 128;
    const int qrow = q0 + w * 32 + ln;

    __shared__ __align__(128) bf16 Ks[2][64 * 128];
    __shared__ __align__(128) bf16 Vt[2][128 * 64];

    bf16x8 qf[8];
    {
        const bf16* qptr = qkv + (size_t)qrow * QKV_N + hq * DH + hi * 8;
#pragma unroll
        for (int s = 0; s < 8; ++s) qf[s] = *(const bf16x8*)(qptr + s * 16);
    }

    const bf16* ksrc = qkv + NH * DH + kvh * DH;
    const bf16* vsrc = vt_g + (size_t)kvh * DH * S_LEN;
    const int kcK = lane & 15;
    const int krs = lane >> 4;
    const int kcV = lane & 7;
    const int vrs = lane >> 3;

    auto stage = [&](int buf, int kt) {
        const int k0s = kt * 64;
#pragma unroll
        for (int j = 0; j < 4; ++j) {
            int r = w * 16 + j * 4 + krs;
            load_lds16(ksrc + (size_t)(k0s + r) * QKV_N + ((kcK ^ (r & 7)) * 8),
                       &Ks[buf][(w * 16 + j * 4) * 128]);
        }
#pragma unroll
        for (int j = 0; j < 4; ++j) {
            int d = w * 32 + j * 8 + vrs;
            load_lds16(vsrc + (size_t)d * S_LEN + k0s + ((kcV ^ (d & 7)) * 8),
                       &Vt[buf][(w * 32 + j * 8) * 64]);
        }
    };

    f32x16 acc[4];
#pragma unroll
    for (int t = 0; t < 4; ++t)
#pragma unroll
        for (int r = 0; r < 16; ++r) acc[t][r] = 0.f;
    float m2 = -1e30f, l = 0.f;

    const int kt_last = (q0 + 127) >> 6;
    int buf = 0;
    stage(0, 0);
    __syncthreads();

    for (int kt = 0; kt <= kt_last; ++kt) {
        if (kt < kt_last) stage(buf ^ 1, kt + 1);
        const int k0 = kt * 64;
        if (k0 <= q0 + w * 32 + 31) {
            f32x16 st[2];
#pragma unroll
            for (int t = 0; t < 2; ++t)
#pragma unroll
                for (int r = 0; r < 16; ++r) st[t][r] = 0.f;
            const bf16* Kb = &Ks[buf][0];
            __builtin_amdgcn_s_setprio(1);
#pragma unroll
            for (int t = 0; t < 2; ++t) {
                const int key = t * 32 + ln;
#pragma unroll
                for (int s = 0; s < 8; ++s) {
                    bf16x8 kf =
                        *(const bf16x8*)&Kb[key * 128 + (((2 * s + hi) ^ (key & 7)) * 8)];
                    st[t] = mfma32(kf, qf[s], st[t]);
                }
            }
            __builtin_amdgcn_s_setprio(0);
            const bool needMask = (k0 + 63 > q0 + w * 32);
            float tmax = -1e30f;
#pragma unroll
            for (int t = 0; t < 2; ++t)
#pragma unroll
                for (int r = 0; r < 16; ++r) {
                    int kcol = k0 + t * 32 + (r & 3) + 8 * (r >> 2) + 4 * hi;
                    float v = st[t][r] * SCALE2_ATT;
                    if (needMask && kcol > qrow) v = -1e30f;
                    st[t][r] = v;
                    tmax = fmaxf(tmax, v);
                }
            tmax = fmaxf(tmax, __shfl_xor(tmax, 32, 64));
            const bool skip = __all(tmax - m2 <= 11.5f);
            float mnew, alpha;
            if (skip) { mnew = m2; alpha = 1.f; }
            else { mnew = fmaxf(m2, tmax); alpha = exp2f(m2 - mnew); }
            float rs = 0.f;
#pragma unroll
            for (int t = 0; t < 2; ++t)
#pragma unroll
                for (int r = 0; r < 16; ++r) {
                    float e = exp2f(st[t][r] - mnew);
                    st[t][r] = e;
                    rs += e;
                }
            rs += __shfl_xor(rs, 32, 64);
            l = l * alpha + rs;
            m2 = mnew;
            if (!skip) {
#pragma unroll
                for (int t = 0; t < 4; ++t)
#pragma unroll
                    for (int r = 0; r < 16; ++r) acc[t][r] *= alpha;
            }
            unsigned cw[16];
#pragma unroll
            for (int i = 0; i < 16; ++i)
                cw[i] = pack2_bf16(st[i >> 3][2 * (i & 7)], st[i >> 3][2 * (i & 7) + 1]);
            bf16x8 pa[4];
#pragma unroll
            for (int ks = 0; ks < 4; ++ks) {
                const int base = (ks >> 1) * 8 + (ks & 1) * 4;
                union { unsigned u[4]; bf16x8 v; } pk;
#pragma unroll
                for (int e = 0; e < 2; ++e) {
                    unsigned A = cw[base + e];
                    unsigned B = cw[base + 2 + e];
                    unsigned tA = (unsigned)__shfl_xor((int)A, 32, 64);
                    unsigned tB = (unsigned)__shfl_xor((int)B, 32, 64);
                    pk.u[e] = hi ? tB : A;
                    pk.u[e + 2] = hi ? B : tA;
                }
                pa[ks] = pk.v;
            }
            const bf16* Vb = &Vt[buf][0];
            __builtin_amdgcn_s_setprio(1);
#pragma unroll
            for (int dt = 0; dt < 4; ++dt) {
                const int d = dt * 32 + ln;
#pragma unroll
                for (int ks = 0; ks < 4; ++ks) {
                    bf16x8 vf =
                        *(const bf16x8*)&Vb[d * 64 + (((2 * ks + hi) ^ (d & 7)) * 8)];
                    acc[dt] = mfma32(vf, pa[ks], acc[dt]);
                }
            }
            __builtin_amdgcn_s_setprio(0);
        }
        __syncthreads();
        buf ^= 1;
    }

    const float invl = 1.f / l;
    bf16* outp = qkv + (size_t)qrow * QKV_N + hq * DH;
#pragma unroll
    for (int dt = 0; dt < 4; ++dt)
#pragma unroll
        for (int rq = 0; rq < 4; ++rq) {
            bf16x4 o;
#pragma unroll
            for (int i = 0; i < 4; ++i) o[i] = (bf16)(acc[dt][rq * 4 + i] * invl);
            *(bf16x4*)(outp + dt * 32 + rq * 8 + hi * 4) = o;
        }
}

extern "C" void kernel_launch(void* const* d_in, const int* in_sizes, int n_in,
                              void* d_out, int out_size, void* d_ws, size_t ws_size,
                              hipStream_t stream) {
    const int* positions = (const int*)d_in[0];
    const float* hidden = (const float*)d_in[1];
    const float* w_qkv = (const float*)d_in[2];
    const float* w_o = (const float*)d_in[3];
    float* out = (float*)d_out;

    const size_t n_qkv = (size_t)S_LEN * QKV_N;
    const size_t n_vt = (size_t)NKV * DH * S_LEN;
    const size_t n_hid = (size_t)S_LEN * HID;
    const size_t n_wqkv = (size_t)QKV_N * HID;
    const size_t n_wo = (size_t)HID * HID;

    const size_t need_min = (n_qkv + n_vt) * sizeof(bf16);
    const size_t need_full = (n_qkv + n_vt + n_hid + n_wqkv + n_wo) * sizeof(bf16);
    if (ws_size < need_min) return;

    bf16* qkv = (bf16*)d_ws;
    bf16* vt_g = qkv + n_qkv;
    bf16* hid_b = vt_g + n_vt;
    bf16* wqkv_b = hid_b + n_hid;
    bf16* wo_b = wqkv_b + n_wqkv;
    const bool full = ws_size >= need_full;

    if (full) {
        const int c0 = (int)(n_hid / 8), c1 = (int)(n_wqkv / 8), c2 = (int)(n_wo / 8);
        cvt3_kernel<<<(c0 + c1 + c2 + 255) / 256, 256, 0, stream>>>(hidden, hid_b, c0,
                                                                    w_qkv, wqkv_b, c1,
                                                                    w_o, wo_b, c2);
        hipFuncSetAttribute(reinterpret_cast<const void*>(&gemm_8ph<256, bf16>),
                            hipFuncAttributeMaxDynamicSharedMemorySize, 131072);
        gemm_8ph<256, bf16><<<dim3(QKV_N / 256, S_LEN / 256), 512, 131072, stream>>>(
            hid_b, wqkv_b, qkv, HID, HID, QKV_N);
    } else {
        gemm_bt<<<dim3(QKV_N / 128, S_LEN / 128), 256, 0, stream>>>(hidden, w_qkv, qkv, HID, HID, QKV_N);
    }
    rope_kernel<<<(S_LEN * 64 + 255) / 256, 256, 0, stream>>>(qkv, positions);
    vtrans_kernel<<<dim3(S_LEN / 64, NKV), 256, 0, stream>>>(qkv, vt_g);
    attn_kernel<<<dim3(NH, S_LEN / 128), 256, 0, stream>>>(qkv, vt_g);
    if (full) {
        hipFuncSetAttribute(reinterpret_cast<const void*>(&gemm_8ph<128, float>),
                            hipFuncAttributeMaxDynamicSharedMemorySize, 98304);
        gemm_8ph<128, float><<<dim3(HID / 128, S_LEN / 256), 512, 98304, stream>>>(
            qkv, wo_b, out, HID, QKV_N, HID);
    } else {
        gemm_bt<<<dim3(HID / 128, S_LEN / 128), 256, 0, stream>>>(qkv, w_o, out, HID, QKV_N, HID);
    }
}

// Round 8
// 515.144 us; speedup vs baseline: 1.0444x; 1.0202x over previous
//
#include <hip/hip_runtime.h>
#include <hip/hip_bf16.h>

#define S_LEN 2048
#define HID 4096
#define NH 32
#define NKV 8
#define DH 128
#define QKV_N ((NH + 2 * NKV) * DH) /* 6144 */
#define SCALE_ATT 0.08838834764831845f /* 128^-0.5 */
#define SCALE2_ATT 0.12751744f         /* SCALE_ATT * log2(e) */

typedef __bf16 bf16;
typedef __bf16 bf16x8 __attribute__((ext_vector_type(8)));
typedef __bf16 bf16x4 __attribute__((ext_vector_type(4)));
typedef float f32x4 __attribute__((ext_vector_type(4)));
typedef float f32x16 __attribute__((ext_vector_type(16)));

__device__ inline f32x4 mfma16(bf16x8 a, bf16x8 b, f32x4 c) {
    return __builtin_amdgcn_mfma_f32_16x16x32_bf16(a, b, c, 0, 0, 0);
}
__device__ inline f32x16 mfma32(bf16x8 a, bf16x8 b, f32x16 c) {
    return __builtin_amdgcn_mfma_f32_32x32x16_bf16(a, b, c, 0, 0, 0);
}

__device__ inline bf16x8 load8(const float* p) {
    const float4 a = ((const float4*)p)[0];
    const float4 b = ((const float4*)p)[1];
    bf16x8 r;
    r[0] = (bf16)a.x; r[1] = (bf16)a.y; r[2] = (bf16)a.z; r[3] = (bf16)a.w;
    r[4] = (bf16)b.x; r[5] = (bf16)b.y; r[6] = (bf16)b.z; r[7] = (bf16)b.w;
    return r;
}
__device__ inline bf16x8 load8(const bf16* p) { return *(const bf16x8*)p; }

// direct global->LDS DMA, 16 bytes/lane. LDS dest is wave-uniform base + lane*16.
__device__ inline void load_lds16(const bf16* g, bf16* lds_base) {
    __builtin_amdgcn_global_load_lds(
        (const __attribute__((address_space(1))) void*)g,
        (__attribute__((address_space(3))) void*)lds_base, 16, 0, 0);
}

// pack 2 f32 -> 1 u32 holding 2 bf16
__device__ inline unsigned pack2_bf16(float lo, float hi) {
    union { bf16 h[2]; unsigned u; } r;
    r.h[0] = (bf16)lo;
    r.h[1] = (bf16)hi;
    return r.u;
}

// fused fp32 -> bf16 bulk convert for three buffers (one launch)
__global__ __launch_bounds__(256) void cvt3_kernel(const float* __restrict__ s0, bf16* __restrict__ d0, int c0,
                                                   const float* __restrict__ s1, bf16* __restrict__ d1, int c1,
                                                   const float* __restrict__ s2, bf16* __restrict__ d2, int c2) {
    int i = blockIdx.x * 256 + threadIdx.x;
    if (i < c0) { *(bf16x8*)&d0[(size_t)i * 8] = load8(&s0[(size_t)i * 8]); return; }
    i -= c0;
    if (i < c1) { *(bf16x8*)&d1[(size_t)i * 8] = load8(&s1[(size_t)i * 8]); return; }
    i -= c1;
    if (i < c2) { *(bf16x8*)&d2[(size_t)i * 8] = load8(&s2[(size_t)i * 8]); }
}

// ---------------------------------------------------------------------------
// 256-row-tile GEMM, 2 half-phases/K-tile, compiler-scheduled inner bodies
// (round-7 proven: GEMMs dropped out of the top-5). See round-7 notes.
// ---------------------------------------------------------------------------
template <int BN, typename OutT>
__global__ __launch_bounds__(512, 2) void gemm_8ph(const bf16* __restrict__ A,
                                                   const bf16* __restrict__ B,
                                                   OutT* __restrict__ C,
                                                   int K, int lda, int ldc) {
    constexpr int WTN = BN / 4;     // per-wave N extent
    constexpr int NREP = WTN / 32;  // 32-wide frags per wave (2 or 1)
    extern __shared__ char smem[];
    bf16* As = (bf16*)smem;                       // [2][256*64]
    bf16* Bs = (bf16*)(smem + 2 * 256 * 64 * 2);  // [2][BN*64]

    const int tid = threadIdx.x;
    const int lane = tid & 63;
    const int w = tid >> 6;     // 0..7
    const int wm = w >> 2;      // 0..1
    const int wn = w & 3;       // 0..3
    const int ln = lane & 31;
    const int hi = lane >> 5;
    const int rseg = lane >> 3;       // row within 8-row staging group
    const int gc = (lane & 7) ^ rseg; // swizzled source chunk

    const int m0 = (int)blockIdx.y * 256;
    const int n0 = (int)blockIdx.x * BN;
    const int NT = K >> 6;

    auto stageA = [&](int pb, int kt, int h) {
        const int k0 = kt * 64;
        const int rb = h * 128 + w * 16;
        const bf16* src = &A[(size_t)(m0 + rb + rseg) * lda + k0 + gc * 8];
        bf16* dst = &As[pb * (256 * 64) + rb * 64];
        load_lds16(src, dst);
        load_lds16(src + (size_t)8 * lda, dst + 8 * 64);
    };
    auto stageB = [&](int pb, int kt, int h) {
        const int k0 = kt * 64;
        if constexpr (BN == 256) {
            const int rb = h * 128 + w * 16;
            const bf16* src = &B[(size_t)(n0 + rb + rseg) * K + k0 + gc * 8];
            bf16* dst = &Bs[pb * (BN * 64) + rb * 64];
            load_lds16(src, dst);
            load_lds16(src + (size_t)8 * K, dst + 8 * 64);
        } else {
            const int rb = h * 64 + w * 8;
            const bf16* src = &B[(size_t)(n0 + rb + rseg) * K + k0 + gc * 8];
            bf16* dst = &Bs[pb * (BN * 64) + rb * 64];
            load_lds16(src, dst);
        }
    };

    f32x16 acc[4][NREP];
#pragma unroll
    for (int mi = 0; mi < 4; ++mi)
#pragma unroll
        for (int j = 0; j < NREP; ++j)
#pragma unroll
            for (int r = 0; r < 16; ++r) acc[mi][j][r] = 0.f;

    // prologue: B_0, A_0 -> parity 0; B_1 -> parity 1
    stageB(0, 0, 0); stageB(0, 0, 1);
    stageA(0, 0, 0); stageA(0, 0, 1);
    {
        const int k1 = NT > 1 ? 1 : 0;
        stageB(1, k1, 0); stageB(1, k1, 1);
    }
    if constexpr (BN == 256)
        asm volatile("s_waitcnt vmcnt(4)" ::: "memory");
    else
        asm volatile("s_waitcnt vmcnt(2)" ::: "memory");
    __builtin_amdgcn_s_barrier();

    int p = 0;
    for (int u = 0; u < NT; ++u, p ^= 1) {
        const bf16* Ab = &As[p * (256 * 64)];
        const bf16* Bb = &Bs[p * (BN * 64)];
        const int ktA = u + 1 < NT ? u + 1 : NT - 1;
        const int ktB = u + 2 < NT ? u + 2 : NT - 1;

        // ---------------- half 1: B-frags + quadrants 0,1 ----------------
        bf16x8 bfr[NREP][4];
#pragma unroll
        for (int j = 0; j < NREP; ++j)
#pragma unroll
            for (int kk = 0; kk < 4; ++kk) {
                const int n = wn * WTN + j * 32 + ln;
                bfr[j][kk] = *(const bf16x8*)&Bb[n * 64 + (((2 * kk + hi) ^ (ln & 7)) * 8)];
            }
        {
            bf16x8 af0[4], af1[4];
#pragma unroll
            for (int kk = 0; kk < 4; ++kk) {
                const int mA = wm * 128 + 0 * 32 + ln;
                const int mB = wm * 128 + 1 * 32 + ln;
                af0[kk] = *(const bf16x8*)&Ab[mA * 64 + (((2 * kk + hi) ^ (ln & 7)) * 8)];
                af1[kk] = *(const bf16x8*)&Ab[mB * 64 + (((2 * kk + hi) ^ (ln & 7)) * 8)];
            }
            stageA(p ^ 1, ktA, 0);
            stageA(p ^ 1, ktA, 1);
#pragma unroll
            for (int j = 0; j < NREP; ++j)
#pragma unroll
                for (int kk = 0; kk < 4; ++kk) {
                    acc[0][j] = mfma32(af0[kk], bfr[j][kk], acc[0][j]);
                    acc[1][j] = mfma32(af1[kk], bfr[j][kk], acc[1][j]);
                }
        }
        asm volatile("s_waitcnt lgkmcnt(0)" ::: "memory"); // WAR: my p-reads done
        __builtin_amdgcn_s_barrier();                      // BARRIER_A

        // ---------------- half 2: quadrants 2,3 ----------------
        {
            bf16x8 af2[4], af3[4];
#pragma unroll
            for (int kk = 0; kk < 4; ++kk) {
                const int mA = wm * 128 + 2 * 32 + ln;
                const int mB = wm * 128 + 3 * 32 + ln;
                af2[kk] = *(const bf16x8*)&Ab[mA * 64 + (((2 * kk + hi) ^ (ln & 7)) * 8)];
                af3[kk] = *(const bf16x8*)&Ab[mB * 64 + (((2 * kk + hi) ^ (ln & 7)) * 8)];
            }
            stageB(p, ktB, 0);
            stageB(p, ktB, 1);
#pragma unroll
            for (int j = 0; j < NREP; ++j)
#pragma unroll
                for (int kk = 0; kk < 4; ++kk) {
                    acc[2][j] = mfma32(af2[kk], bfr[j][kk], acc[2][j]);
                    acc[3][j] = mfma32(af3[kk], bfr[j][kk], acc[3][j]);
                }
        }
        if constexpr (BN == 256)
            asm volatile("s_waitcnt vmcnt(4)" ::: "memory");
        else
            asm volatile("s_waitcnt vmcnt(2)" ::: "memory");
        asm volatile("s_waitcnt lgkmcnt(0)" ::: "memory");
        __builtin_amdgcn_s_barrier();                        // BARRIER_B
    }
    asm volatile("s_waitcnt vmcnt(0)" ::: "memory");

    // epilogue
#pragma unroll
    for (int mi = 0; mi < 4; ++mi)
#pragma unroll
        for (int j = 0; j < NREP; ++j)
#pragma unroll
            for (int r = 0; r < 16; ++r) {
                int row = m0 + wm * 128 + mi * 32 + (r & 3) + 8 * (r >> 2) + 4 * hi;
                int col = n0 + wn * WTN + j * 32 + ln;
                C[(size_t)row * ldc + col] = (OutT)acc[mi][j][r];
            }
}

// ---------------- fallback fp32-staging GEMM (low-workspace path) ----------------
template <typename AT, typename OutT>
__global__ __launch_bounds__(256) void gemm_bt(const AT* __restrict__ A,
                                               const float* __restrict__ B,
                                               OutT* __restrict__ C,
                                               int K, int lda, int ldc) {
    const int tid = threadIdx.x;
    const int lane = tid & 63;
    const int w = tid >> 6;
    const int m0 = blockIdx.y * 128;
    const int n0 = blockIdx.x * 128;
    const int wm = (w >> 1) * 64;
    const int wn = (w & 1) * 64;
    const int ln = lane & 15;
    const int qo = lane >> 4;

    __shared__ bf16 As[128 * 72];
    __shared__ bf16 Bs[128 * 72];

    f32x4 acc[4][4];
#pragma unroll
    for (int mi = 0; mi < 4; ++mi)
#pragma unroll
        for (int ni = 0; ni < 4; ++ni) acc[mi][ni] = f32x4{0.f, 0.f, 0.f, 0.f};

    for (int k0 = 0; k0 < K; k0 += 64) {
#pragma unroll
        for (int i = 0; i < 4; ++i) {
            int v = tid + i * 256;
            int row = v >> 3;
            int col = (v & 7) * 8;
            *(bf16x8*)&As[row * 72 + col] = load8(&A[(size_t)(m0 + row) * lda + k0 + col]);
            *(bf16x8*)&Bs[row * 72 + col] = load8(&B[(size_t)(n0 + row) * K + k0 + col]);
        }
        __syncthreads();
#pragma unroll
        for (int kk = 0; kk < 64; kk += 32) {
            bf16x8 af[4], bfr[4];
#pragma unroll
            for (int mi = 0; mi < 4; ++mi)
                af[mi] = *(const bf16x8*)&As[(wm + mi * 16 + ln) * 72 + kk + qo * 8];
#pragma unroll
            for (int ni = 0; ni < 4; ++ni)
                bfr[ni] = *(const bf16x8*)&Bs[(wn + ni * 16 + ln) * 72 + kk + qo * 8];
#pragma unroll
            for (int mi = 0; mi < 4; ++mi)
#pragma unroll
                for (int ni = 0; ni < 4; ++ni)
                    acc[mi][ni] = mfma16(af[mi], bfr[ni], acc[mi][ni]);
        }
        __syncthreads();
    }
#pragma unroll
    for (int mi = 0; mi < 4; ++mi)
#pragma unroll
        for (int ni = 0; ni < 4; ++ni)
#pragma unroll
            for (int r = 0; r < 4; ++r) {
                int row = m0 + wm + mi * 16 + qo * 4 + r;
                int col = n0 + wn + ni * 16 + ln;
                C[(size_t)row * ldc + col] = (OutT)acc[mi][ni][r];
            }
}

// RoPE: one thread per (s, d); trig computed once, reused across all 40
// rotated heads. Q heads (h < NH) additionally pre-scaled by SCALE2_ATT
// (= D^-0.5 * log2e) so attention's softmax skips the per-element scale
// (QK^T output lands directly in the log2 domain).
__global__ __launch_bounds__(256) void rope_kernel(bf16* __restrict__ qkv,
                                                   const int* __restrict__ positions) {
    int idx = blockIdx.x * 256 + threadIdx.x;
    if (idx >= S_LEN * 64) return;
    int d = idx & 63;
    int s = idx >> 6;
    float pos = (float)positions[s];
    float inv = expf(-0.21586735246819178f * (float)d); // 1e6^(-d/64)
    float ang = pos * inv;
    float sn, c;
    sincosf(ang, &sn, &c);
    const size_t row = (size_t)s * QKV_N;
#pragma unroll 8
    for (int h = 0; h < NH + NKV; ++h) {
        const float sc = (h < NH) ? SCALE2_ATT : 1.f;
        size_t base = row + (size_t)h * DH;
        float x1 = (float)qkv[base + d];
        float x2 = (float)qkv[base + d + 64];
        qkv[base + d] = (bf16)((x1 * c - x2 * sn) * sc);
        qkv[base + d + 64] = (bf16)((x2 * c + x1 * sn) * sc);
    }
}

// Pre-transpose V into vt_g[kvh][d][s]
__global__ __launch_bounds__(256) void vtrans_kernel(const bf16* __restrict__ qkv,
                                                     bf16* __restrict__ vt_g) {
    const int tid = threadIdx.x;
    const int s0 = blockIdx.x * 64;
    const int kvh = blockIdx.y;
    __shared__ bf16 Ls[64 * 136];
#pragma unroll
    for (int i = 0; i < 4; ++i) {
        int v = tid + i * 256;
        int row = v >> 4;
        int col = (v & 15) * 8;
        *(bf16x8*)&Ls[row * 136 + col] =
            *(const bf16x8*)&qkv[(size_t)(s0 + row) * QKV_N + (NH + NKV) * DH + kvh * DH + col];
    }
    __syncthreads();
#pragma unroll
    for (int i = 0; i < 4; ++i) {
        int u = tid + i * 256;
        int d = u >> 3;
        int sg = (u & 7) * 8;
        bf16x8 r;
#pragma unroll
        for (int j = 0; j < 8; ++j) r[j] = Ls[(sg + j) * 136 + d];
        *(bf16x8*)&vt_g[((size_t)kvh * DH + d) * S_LEN + s0 + sg] = r;
    }
}

// ---------------------------------------------------------------------------
// Flash attention. Round-8 changes: (1) BALANCED qtile map — co-resident
// blocks are (hq, y) and (hq, y+8) (XCD %8 round-robin, stride-256 CU
// pairing); map qtile = (y<8) ? y : 23-y so every CU pair sums to a uniform
// 36 K-tile-units (was 48-4y, 1.41x wall inflation). (2) Q pre-scaled in
// RoPE -> no per-element scale in softmax.
// ---------------------------------------------------------------------------
__global__ __launch_bounds__(256) void attn_kernel(bf16* __restrict__ qkv,
                                                   const bf16* __restrict__ vt_g) {
    const int tid = threadIdx.x;
    const int lane = tid & 63;
    const int w = tid >> 6;
    const int ln = lane & 31;
    const int hi = lane >> 5;
    const int hq = blockIdx.x;
    const int y = (int)blockIdx.y;
    const int qtile = (y < 8) ? y : 23 - y; // balanced pairing (y, y+8) -> 36 units
    const int kvh = hq >> 2;
    const int q0 = qtile * 128;
    const int qrow = q0 + w * 32 + ln;

    __shared__ __align__(128) bf16 Ks[2][64 * 128];
    __shared__ __align__(128) bf16 Vt[2][128 * 64];

    bf16x8 qf[8];
    {
        const bf16* qptr = qkv + (size_t)qrow * QKV_N + hq * DH + hi * 8;
#pragma unroll
        for (int s = 0; s < 8; ++s) qf[s] = *(const bf16x8*)(qptr + s * 16);
    }

    const bf16* ksrc = qkv + NH * DH + kvh * DH;
    const bf16* vsrc = vt_g + (size_t)kvh * DH * S_LEN;
    const int kcK = lane & 15;
    const int krs = lane >> 4;
    const int kcV = lane & 7;
    const int vrs = lane >> 3;

    auto stage = [&](int buf, int kt) {
        const int k0s = kt * 64;
#pragma unroll
        for (int j = 0; j < 4; ++j) {
            int r = w * 16 + j * 4 + krs;
            load_lds16(ksrc + (size_t)(k0s + r) * QKV_N + ((kcK ^ (r & 7)) * 8),
                       &Ks[buf][(w * 16 + j * 4) * 128]);
        }
#pragma unroll
        for (int j = 0; j < 4; ++j) {
            int d = w * 32 + j * 8 + vrs;
            load_lds16(vsrc + (size_t)d * S_LEN + k0s + ((kcV ^ (d & 7)) * 8),
                       &Vt[buf][(w * 32 + j * 8) * 64]);
        }
    };

    f32x16 acc[4];
#pragma unroll
    for (int t = 0; t < 4; ++t)
#pragma unroll
        for (int r = 0; r < 16; ++r) acc[t][r] = 0.f;
    float m2 = -1e30f, l = 0.f;

    const int kt_last = (q0 + 127) >> 6;
    int buf = 0;
    stage(0, 0);
    __syncthreads();

    for (int kt = 0; kt <= kt_last; ++kt) {
        if (kt < kt_last) stage(buf ^ 1, kt + 1);
        const int k0 = kt * 64;
        if (k0 <= q0 + w * 32 + 31) {
            f32x16 st[2];
#pragma unroll
            for (int t = 0; t < 2; ++t)
#pragma unroll
                for (int r = 0; r < 16; ++r) st[t][r] = 0.f;
            const bf16* Kb = &Ks[buf][0];
            __builtin_amdgcn_s_setprio(1);
#pragma unroll
            for (int t = 0; t < 2; ++t) {
                const int key = t * 32 + ln;
#pragma unroll
                for (int s = 0; s < 8; ++s) {
                    bf16x8 kf =
                        *(const bf16x8*)&Kb[key * 128 + (((2 * s + hi) ^ (key & 7)) * 8)];
                    st[t] = mfma32(kf, qf[s], st[t]);
                }
            }
            __builtin_amdgcn_s_setprio(0);
            const bool needMask = (k0 + 63 > q0 + w * 32);
            float tmax = -1e30f;
#pragma unroll
            for (int t = 0; t < 2; ++t)
#pragma unroll
                for (int r = 0; r < 16; ++r) {
                    int kcol = k0 + t * 32 + (r & 3) + 8 * (r >> 2) + 4 * hi;
                    float v = st[t][r]; // already log2-scaled (Q pre-scaled in RoPE)
                    if (needMask && kcol > qrow) v = -1e30f;
                    st[t][r] = v;
                    tmax = fmaxf(tmax, v);
                }
            tmax = fmaxf(tmax, __shfl_xor(tmax, 32, 64));
            const bool skip = __all(tmax - m2 <= 11.5f);
            float mnew, alpha;
            if (skip) { mnew = m2; alpha = 1.f; }
            else { mnew = fmaxf(m2, tmax); alpha = exp2f(m2 - mnew); }
            float rs = 0.f;
#pragma unroll
            for (int t = 0; t < 2; ++t)
#pragma unroll
                for (int r = 0; r < 16; ++r) {
                    float e = exp2f(st[t][r] - mnew);
                    st[t][r] = e;
                    rs += e;
                }
            rs += __shfl_xor(rs, 32, 64);
            l = l * alpha + rs;
            m2 = mnew;
            if (!skip) {
#pragma unroll
                for (int t = 0; t < 4; ++t)
#pragma unroll
                    for (int r = 0; r < 16; ++r) acc[t][r] *= alpha;
            }
            unsigned cw[16];
#pragma unroll
            for (int i = 0; i < 16; ++i)
                cw[i] = pack2_bf16(st[i >> 3][2 * (i & 7)], st[i >> 3][2 * (i & 7) + 1]);
            bf16x8 pa[4];
#pragma unroll
            for (int ks = 0; ks < 4; ++ks) {
                const int base = (ks >> 1) * 8 + (ks & 1) * 4;
                union { unsigned u[4]; bf16x8 v; } pk;
#pragma unroll
                for (int e = 0; e < 2; ++e) {
                    unsigned A = cw[base + e];
                    unsigned B = cw[base + 2 + e];
                    unsigned tA = (unsigned)__shfl_xor((int)A, 32, 64);
                    unsigned tB = (unsigned)__shfl_xor((int)B, 32, 64);
                    pk.u[e] = hi ? tB : A;
                    pk.u[e + 2] = hi ? B : tA;
                }
                pa[ks] = pk.v;
            }
            const bf16* Vb = &Vt[buf][0];
            __builtin_amdgcn_s_setprio(1);
#pragma unroll
            for (int dt = 0; dt < 4; ++dt) {
                const int d = dt * 32 + ln;
#pragma unroll
                for (int ks = 0; ks < 4; ++ks) {
                    bf16x8 vf =
                        *(const bf16x8*)&Vb[d * 64 + (((2 * ks + hi) ^ (d & 7)) * 8)];
                    acc[dt] = mfma32(vf, pa[ks], acc[dt]);
                }
            }
            __builtin_amdgcn_s_setprio(0);
        }
        __syncthreads();
        buf ^= 1;
    }

    const float invl = 1.f / l;
    bf16* outp = qkv + (size_t)qrow * QKV_N + hq * DH;
#pragma unroll
    for (int dt = 0; dt < 4; ++dt)
#pragma unroll
        for (int rq = 0; rq < 4; ++rq) {
            bf16x4 o;
#pragma unroll
            for (int i = 0; i < 4; ++i) o[i] = (bf16)(acc[dt][rq * 4 + i] * invl);
            *(bf16x4*)(outp + dt * 32 + rq * 8 + hi * 4) = o;
        }
}

extern "C" void kernel_launch(void* const* d_in, const int* in_sizes, int n_in,
                              void* d_out, int out_size, void* d_ws, size_t ws_size,
                              hipStream_t stream) {
    const int* positions = (const int*)d_in[0];
    const float* hidden = (const float*)d_in[1];
    const float* w_qkv = (const float*)d_in[2];
    const float* w_o = (const float*)d_in[3];
    float* out = (float*)d_out;

    const size_t n_qkv = (size_t)S_LEN * QKV_N;
    const size_t n_vt = (size_t)NKV * DH * S_LEN;
    const size_t n_hid = (size_t)S_LEN * HID;
    const size_t n_wqkv = (size_t)QKV_N * HID;
    const size_t n_wo = (size_t)HID * HID;

    const size_t need_min = (n_qkv + n_vt) * sizeof(bf16);
    const size_t need_full = (n_qkv + n_vt + n_hid + n_wqkv + n_wo) * sizeof(bf16);
    if (ws_size < need_min) return;

    bf16* qkv = (bf16*)d_ws;
    bf16* vt_g = qkv + n_qkv;
    bf16* hid_b = vt_g + n_vt;
    bf16* wqkv_b = hid_b + n_hid;
    bf16* wo_b = wqkv_b + n_wqkv;
    const bool full = ws_size >= need_full;

    if (full) {
        const int c0 = (int)(n_hid / 8), c1 = (int)(n_wqkv / 8), c2 = (int)(n_wo / 8);
        cvt3_kernel<<<(c0 + c1 + c2 + 255) / 256, 256, 0, stream>>>(hidden, hid_b, c0,
                                                                    w_qkv, wqkv_b, c1,
                                                                    w_o, wo_b, c2);
        hipFuncSetAttribute(reinterpret_cast<const void*>(&gemm_8ph<256, bf16>),
                            hipFuncAttributeMaxDynamicSharedMemorySize, 131072);
        gemm_8ph<256, bf16><<<dim3(QKV_N / 256, S_LEN / 256), 512, 131072, stream>>>(
            hid_b, wqkv_b, qkv, HID, HID, QKV_N);
    } else {
        gemm_bt<<<dim3(QKV_N / 128, S_LEN / 128), 256, 0, stream>>>(hidden, w_qkv, qkv, HID, HID, QKV_N);
    }
    rope_kernel<<<(S_LEN * 64 + 255) / 256, 256, 0, stream>>>(qkv, positions);
    vtrans_kernel<<<dim3(S_LEN / 64, NKV), 256, 0, stream>>>(qkv, vt_g);
    attn_kernel<<<dim3(NH, S_LEN / 128), 256, 0, stream>>>(qkv, vt_g);
    if (full) {
        hipFuncSetAttribute(reinterpret_cast<const void*>(&gemm_8ph<128, float>),
                            hipFuncAttributeMaxDynamicSharedMemorySize, 98304);
        gemm_8ph<128, float><<<dim3(HID / 128, S_LEN / 256), 512, 98304, stream>>>(
            qkv, wo_b, out, HID, QKV_N, HID);
    } else {
        gemm_bt<<<dim3(HID / 128, S_LEN / 128), 256, 0, stream>>>(qkv, w_o, out, HID, QKV_N, HID);
    }
}